// Round 2
// baseline (2804.698 us; speedup 1.0000x reference)
//
#include <hip/hip_runtime.h>
#include <hip/hip_bf16.h>

#define LL 24
#define NN 16384
#define HH 128
#define DIN 136          // 16 (op) + 56 (attr) + 32 (fd) + 32 (od)
#define KTOT 264         // DIN + HH
#define G4 512
#define LN (LL*NN)

__device__ __forceinline__ float sigm(float x){ return 1.f/(1.f+__expf(-x)); }
__device__ __forceinline__ float tanhfast(float x){
    float e = __expf(-2.f*fabsf(x));
    float t = (1.f-e)/(1.f+e);
    return x >= 0.f ? t : -t;
}

// ---------------------------------------------------------------------------
// act = leaky(X @ W.T + b), plus per-channel sum / sumsq for BN stats.
// Tile: 128 rows x 32 ch per block-iteration; thread = (rg 0..15) x (c2 0..15),
// owns 8 rows x 2 channels.
// ---------------------------------------------------------------------------
template<int D>
__global__ __launch_bounds__(256) void act_kernel(
    const float* __restrict__ X, const float* __restrict__ W,
    const float* __restrict__ bias, float* __restrict__ act,
    float* __restrict__ sums /* [0..31]=sum, [32..63]=sumsq */)
{
    __shared__ float w_lds[D*32];
    __shared__ float xs[128*D];
    const int tid = threadIdx.x;
    for (int i = tid; i < D*32; i += 256) {
        int k = i >> 5, ch = i & 31;
        w_lds[i] = W[ch*D + k];            // stored transposed: [k][ch]
    }
    const int c2 = tid & 15;
    const int rg = tid >> 4;
    const int ch0 = 2*c2, ch1 = ch0+1;
    const float b0 = bias[ch0], b1 = bias[ch1];
    float s0=0.f,s1=0.f,q0=0.f,q1=0.f;
    for (int tile = blockIdx.x; tile < LN/128; tile += gridDim.x) {
        const long row0 = (long)tile*128;
        __syncthreads();
        for (int i = tid; i < 128*D; i += 256) xs[i] = X[row0*D + i];
        __syncthreads();
        float a0[8], a1[8];
        #pragma unroll
        for (int i=0;i<8;++i){ a0[i]=b0; a1[i]=b1; }
        for (int k=0;k<D;++k){
            float w0 = w_lds[(k<<5)+ch0];
            float w1 = w_lds[(k<<5)+ch1];
            #pragma unroll
            for (int i=0;i<8;++i){
                float x = xs[(rg*8+i)*D + k];
                a0[i] = fmaf(x,w0,a0[i]);
                a1[i] = fmaf(x,w1,a1[i]);
            }
        }
        #pragma unroll
        for (int i=0;i<8;++i){
            float v0 = a0[i]; v0 = v0>0.f ? v0 : 0.01f*v0;
            float v1 = a1[i]; v1 = v1>0.f ? v1 : 0.01f*v1;
            *(float2*)&act[(row0 + rg*8+i)*32 + ch0] = make_float2(v0,v1);
            s0+=v0; q0+=v0*v0; s1+=v1; q1+=v1*v1;
        }
    }
    __syncthreads();
    float* red = xs;                        // reuse LDS
    red[tid]=s0; red[256+tid]=q0; red[512+tid]=s1; red[768+tid]=q1;
    __syncthreads();
    if (tid < 16) {
        float ts0=0,tq0=0,ts1=0,tq1=0;
        for (int r=0;r<16;++r){
            int t = (r<<4) | tid;
            ts0+=red[t]; tq0+=red[256+t]; ts1+=red[512+t]; tq1+=red[768+t];
        }
        atomicAdd(&sums[2*tid],      ts0);
        atomicAdd(&sums[2*tid+1],    ts1);
        atomicAdd(&sums[32+2*tid],   tq0);
        atomicAdd(&sums[32+2*tid+1], tq1);
    }
}

// ---------------------------------------------------------------------------
// Wt[k][j] = (k<136 ? Wih[j][k] : Whh[j][k-136]); b4[j] = bih[j]+bhh[j]
// ---------------------------------------------------------------------------
__global__ void prep_weights(const float* __restrict__ Wih, const float* __restrict__ Whh,
                             const float* __restrict__ bih, const float* __restrict__ bhh,
                             float* __restrict__ Wt, float* __restrict__ b4)
{
    int k = blockIdx.x, j = threadIdx.x;
    float v = (k < DIN) ? Wih[(long)j*DIN + k] : Whh[(long)j*HH + (k-DIN)];
    Wt[(long)k*G4 + j] = v;
    if (k == 0) b4[j] = bih[j] + bhh[j];
}

// ---------------------------------------------------------------------------
// Finalize BN scale/shift and collapse W2@W1 head into one 128-vector.
// stats layout: [sum_f 32][sumsq_f 32][sum_o 32][sumsq_o 32]
// ss layout:    [scale_f 32][shift_f 32][scale_o 32][shift_o 32]
// wvb layout:   [wv 128][wb 1]
// ---------------------------------------------------------------------------
__global__ void prep_stats(const float* __restrict__ stats,
    const float* __restrict__ g1, const float* __restrict__ beta1,
    const float* __restrict__ g2, const float* __restrict__ beta2,
    const float* __restrict__ W1, const float* __restrict__ b1,
    const float* __restrict__ W2, const float* __restrict__ b2,
    float* __restrict__ ss, float* __restrict__ wvb)
{
    const int t = threadIdx.x;
    const float inv = 1.f/(float)LN;
    if (t < 32) {
        float mean = stats[t]*inv;
        float var  = stats[32+t]*inv - mean*mean;
        float sc = g1[t]/sqrtf(var + 1e-5f);
        ss[t] = sc; ss[32+t] = beta1[t] - mean*sc;
    } else if (t < 64) {
        int c = t - 32;
        float mean = stats[64+c]*inv;
        float var  = stats[96+c]*inv - mean*mean;
        float sc = g2[c]/sqrtf(var + 1e-5f);
        ss[64+c] = sc; ss[96+c] = beta2[c] - mean*sc;
    }
    float s = 0.f;
    for (int a=0;a<20;++a) s += W2[a]*W1[a*HH + t];
    wvb[t] = s;
    if (t == 0) {
        float sb = 0.f;
        for (int a=0;a<20;++a) sb += W2[a]*b1[a];
        wvb[128] = sb + b2[0];
    }
}

// ---------------------------------------------------------------------------
// One LSTM scan step (layer l). 32 rows/block, 256 threads (4 waves).
// Wave w owns rows w*8..w*8+7; lane owns cols {2*lane, 2*lane+1} in all 4
// gate quadrants -> i,f,g,o for a cell live in one thread.
// ---------------------------------------------------------------------------
__global__ __launch_bounds__(256) void lstm_step(
    const float* __restrict__ op, const float* __restrict__ attr,
    const float* __restrict__ actf, const float* __restrict__ acto,
    const int* __restrict__ map, const float* __restrict__ ss,
    const float* __restrict__ Wt, const float* __restrict__ b4,
    const float* __restrict__ h_prev, const float* __restrict__ c_prev,
    float* __restrict__ h_next, float* __restrict__ c_next,
    int l, int first)
{
    __shared__ float xh[32*KTOT];          // 33.8 KB: [row][x(136) | gh(128)]
    const int tid = threadIdx.x;
    const int n0 = blockIdx.x * 32;
    const long lbase = (long)l * NN;

    // stage x = [op(16), attr(56), BN(actf)(32), BN(acto)(32)], BN folded
    for (int i = tid; i < 32*DIN; i += 256) {
        int r = i / DIN, k = i - r*DIN;
        long e = lbase + n0 + r;
        float v;
        if (k < 16)       v = op[e*16 + k];
        else if (k < 72)  v = attr[e*56 + (k-16)];
        else if (k < 104) { int ch=k-72;  v = fmaf(actf[e*32+ch], ss[ch],    ss[32+ch]); }
        else              { int ch=k-104; v = fmaf(acto[e*32+ch], ss[64+ch], ss[96+ch]); }
        xh[r*KTOT + k] = v;
    }
    // stage gh = 0.5 * sum(masked gather of h_prev)
    if (first) {
        for (int i = tid; i < 32*HH; i += 256) {
            int r = i >> 7, j = i & 127;
            xh[r*KTOT + DIN + j] = 0.f;
        }
    } else {
        for (int i = tid; i < 32*HH; i += 256) {
            int r = i >> 7, j = i & 127;
            long e = (lbase + n0 + r)*2;
            int m0 = map[e], m1 = map[e+1];
            float g = 0.f;
            if (m0) g += h_prev[(long)(m0-1)*HH + j];
            if (m1) g += h_prev[(long)(m1-1)*HH + j];
            xh[r*KTOT + DIN + j] = 0.5f*g;
        }
    }
    __syncthreads();

    const int lane = tid & 63;
    const int wv   = tid >> 6;
    const int r0   = wv * 8;
    const int mc   = lane*2;
    float acc[8][4][2];
    #pragma unroll
    for (int q=0;q<4;++q){
        const float2 b = *(const float2*)&b4[q*128 + mc];
        #pragma unroll
        for (int i=0;i<8;++i){ acc[i][q][0]=b.x; acc[i][q][1]=b.y; }
    }
    #pragma unroll 2
    for (int k=0;k<KTOT;++k){
        float2 w0 = *(const float2*)&Wt[(long)k*G4 + 0*128 + mc];
        float2 w1 = *(const float2*)&Wt[(long)k*G4 + 1*128 + mc];
        float2 w2 = *(const float2*)&Wt[(long)k*G4 + 2*128 + mc];
        float2 w3 = *(const float2*)&Wt[(long)k*G4 + 3*128 + mc];
        #pragma unroll
        for (int i=0;i<8;++i){
            float x = xh[(r0+i)*KTOT + k];   // wave-uniform -> LDS broadcast
            acc[i][0][0] = fmaf(x,w0.x,acc[i][0][0]);
            acc[i][0][1] = fmaf(x,w0.y,acc[i][0][1]);
            acc[i][1][0] = fmaf(x,w1.x,acc[i][1][0]);
            acc[i][1][1] = fmaf(x,w1.y,acc[i][1][1]);
            acc[i][2][0] = fmaf(x,w2.x,acc[i][2][0]);
            acc[i][2][1] = fmaf(x,w2.y,acc[i][2][1]);
            acc[i][3][0] = fmaf(x,w3.x,acc[i][3][0]);
            acc[i][3][1] = fmaf(x,w3.y,acc[i][3][1]);
        }
    }

    // epilogue: gather gc from c_prev (wave-uniform row -> coalesced), LSTM cell
    #pragma unroll
    for (int i=0;i<8;++i){
        const int n = n0 + r0 + i;
        float gc0=0.f, gc1=0.f;
        if (!first){
            long e = (lbase + n)*2;
            int m0 = map[e], m1 = map[e+1];
            if (m0){ float2 c = *(const float2*)&c_prev[(long)(m0-1)*HH + mc]; gc0+=c.x; gc1+=c.y; }
            if (m1){ float2 c = *(const float2*)&c_prev[(long)(m1-1)*HH + mc]; gc0+=c.x; gc1+=c.y; }
            gc0*=0.5f; gc1*=0.5f;
        }
        float c0 = sigm(acc[i][1][0])*gc0 + sigm(acc[i][0][0])*tanhfast(acc[i][2][0]);
        float c1 = sigm(acc[i][1][1])*gc1 + sigm(acc[i][0][1])*tanhfast(acc[i][2][1]);
        float h0 = sigm(acc[i][3][0])*tanhfast(c0);
        float h1 = sigm(acc[i][3][1])*tanhfast(c1);
        *(float2*)&c_next[(long)n*HH + mc] = make_float2(c0,c1);
        *(float2*)&h_next[(long)n*HH + mc] = make_float2(h0,h1);
    }
}

// ---------------------------------------------------------------------------
// out[n] = sigmoid(h[n] . wv + wb); one wave per row.
// ---------------------------------------------------------------------------
__global__ __launch_bounds__(256) void final_k(
    const float* __restrict__ h, const float* __restrict__ wvb,
    float* __restrict__ out, int rows)
{
    int gt = blockIdx.x*256 + threadIdx.x;
    int row = gt >> 6;
    int lane = gt & 63;
    if (row >= rows) return;
    float v = fmaf(h[(long)row*HH + lane], wvb[lane],
                   h[(long)row*HH + 64 + lane] * wvb[64+lane]);
    #pragma unroll
    for (int off=32; off>0; off>>=1) v += __shfl_down(v, off);
    if (lane == 0) out[row] = sigm(v + wvb[128]);
}

extern "C" void kernel_launch(void* const* d_in, const int* in_sizes, int n_in,
                              void* d_out, int out_size, void* d_ws, size_t ws_size,
                              hipStream_t stream)
{
    const float* op      = (const float*)d_in[0];
    const float* attr    = (const float*)d_in[1];
    const float* filt    = (const float*)d_in[2];
    const float* outp    = (const float*)d_in[3];
    const int*   mapping = (const int*)d_in[4];
    const float* Wf  = (const float*)d_in[6];
    const float* bf  = (const float*)d_in[7];
    const float* Wo  = (const float*)d_in[8];
    const float* bo  = (const float*)d_in[9];
    const float* g1  = (const float*)d_in[10];
    const float* be1 = (const float*)d_in[11];
    const float* g2  = (const float*)d_in[12];
    const float* be2 = (const float*)d_in[13];
    const float* Wih = (const float*)d_in[14];
    const float* Whh = (const float*)d_in[15];
    const float* bih = (const float*)d_in[16];
    const float* bhh = (const float*)d_in[17];
    const float* W1  = (const float*)d_in[18];
    const float* b1  = (const float*)d_in[19];
    const float* W2  = (const float*)d_in[20];
    const float* b2  = (const float*)d_in[21];

    float* ws   = (float*)d_ws;
    float* actf = ws;                                   // LN*32
    float* acto = actf + (size_t)LN*32;                 // LN*32
    float* h0   = acto + (size_t)LN*32;                 // NN*HH
    float* h1   = h0 + (size_t)NN*HH;
    float* c0   = h1 + (size_t)NN*HH;
    float* c1   = c0 + (size_t)NN*HH;
    float* Wt   = c1 + (size_t)NN*HH;                   // KTOT*G4
    float* b4   = Wt + (size_t)KTOT*G4;                 // 512
    float* stats= b4 + G4;                              // 128
    float* ssb  = stats + 128;                          // 128
    float* wvb  = ssb + 128;                            // 129

    hipMemsetAsync(stats, 0, 128*sizeof(float), stream);
    act_kernel<74><<<768, 256, 0, stream>>>(filt, Wf, bf, actf, stats);
    act_kernel<32><<<768, 256, 0, stream>>>(outp, Wo, bo, acto, stats+64);
    prep_weights<<<KTOT, 512, 0, stream>>>(Wih, Whh, bih, bhh, Wt, b4);
    prep_stats<<<1, 128, 0, stream>>>(stats, g1, be1, g2, be2, W1, b1, W2, b2, ssb, wvb);

    float* hb[2] = {h0, h1};
    float* cb[2] = {c0, c1};
    for (int t = 0; t < LL; ++t) {
        lstm_step<<<NN/32, 256, 0, stream>>>(op, attr, actf, acto, mapping, ssb, Wt, b4,
            hb[t&1], cb[t&1], hb[(t+1)&1], cb[(t+1)&1], (LL-1)-t, t==0);
    }
    final_k<<<(out_size*64 + 255)/256, 256, 0, stream>>>(hb[0], wvb, (float*)d_out, out_size);
}

// Round 3
// 1346.440 us; speedup vs baseline: 2.0830x; 2.0830x over previous
//
#include <hip/hip_runtime.h>
#include <hip/hip_bf16.h>

#define LL 24
#define NN 16384
#define HH 128
#define KP 288           // padded K: 16 op + 56 attr + 32 fd + 32 od + 24 zero + 128 gh
#define LN (LL*NN)

typedef __bf16 bf16;
typedef __attribute__((ext_vector_type(8))) __bf16 bf16x8;
typedef __attribute__((ext_vector_type(2))) __bf16 bf16x2;
typedef __attribute__((ext_vector_type(4))) float f32x4;

__device__ __forceinline__ float sigm(float x){ return 1.f/(1.f+__expf(-x)); }
__device__ __forceinline__ float tanhfast(float x){
    float e = __expf(-2.f*fabsf(x));
    float t = (1.f-e)/(1.f+e);
    return x >= 0.f ? t : -t;
}
__device__ __forceinline__ void gld16(const void* g, void* l){
    __builtin_amdgcn_global_load_lds(
        (const __attribute__((address_space(1))) void*)g,
        (__attribute__((address_space(3))) void*)l, 16, 0, 0);
}

// ---------------------------------------------------------------------------
// act = leaky(X @ W.T + b) -> bf16, plus f32 per-channel sum/sumsq for BN.
// ---------------------------------------------------------------------------
template<int D>
__global__ __launch_bounds__(256) void act_kernel(
    const float* __restrict__ X, const float* __restrict__ W,
    const float* __restrict__ bias, bf16* __restrict__ act,
    float* __restrict__ sums)
{
    __shared__ float w_lds[D*32];
    __shared__ float xs[128*D];
    const int tid = threadIdx.x;
    for (int i = tid; i < D*32; i += 256) {
        int k = i >> 5, ch = i & 31;
        w_lds[i] = W[ch*D + k];
    }
    const int c2 = tid & 15;
    const int rg = tid >> 4;
    const int ch0 = 2*c2, ch1 = ch0+1;
    const float b0 = bias[ch0], b1 = bias[ch1];
    float s0=0.f,s1=0.f,q0=0.f,q1=0.f;
    for (int tile = blockIdx.x; tile < LN/128; tile += gridDim.x) {
        const long row0 = (long)tile*128;
        __syncthreads();
        for (int i = tid; i < 128*D; i += 256) xs[i] = X[row0*D + i];
        __syncthreads();
        float a0[8], a1[8];
        #pragma unroll
        for (int i=0;i<8;++i){ a0[i]=b0; a1[i]=b1; }
        for (int k=0;k<D;++k){
            float w0 = w_lds[(k<<5)+ch0];
            float w1 = w_lds[(k<<5)+ch1];
            #pragma unroll
            for (int i=0;i<8;++i){
                float x = xs[(rg*8+i)*D + k];
                a0[i] = fmaf(x,w0,a0[i]);
                a1[i] = fmaf(x,w1,a1[i]);
            }
        }
        #pragma unroll
        for (int i=0;i<8;++i){
            float v0 = a0[i]; v0 = v0>0.f ? v0 : 0.01f*v0;
            float v1 = a1[i]; v1 = v1>0.f ? v1 : 0.01f*v1;
            bf16x2 pk; pk[0]=(bf16)v0; pk[1]=(bf16)v1;
            *(bf16x2*)&act[(row0 + rg*8+i)*32 + ch0] = pk;
            s0+=v0; q0+=v0*v0; s1+=v1; q1+=v1*v1;
        }
    }
    __syncthreads();
    float* red = xs;
    red[tid]=s0; red[256+tid]=q0; red[512+tid]=s1; red[768+tid]=q1;
    __syncthreads();
    if (tid < 16) {
        float ts0=0,tq0=0,ts1=0,tq1=0;
        for (int r=0;r<16;++r){
            int t = (r<<4) | tid;
            ts0+=red[t]; tq0+=red[256+t]; ts1+=red[512+t]; tq1+=red[768+t];
        }
        atomicAdd(&sums[2*tid],      ts0);
        atomicAdd(&sums[2*tid+1],    ts1);
        atomicAdd(&sums[32+2*tid],   tq0);
        atomicAdd(&sums[32+2*tid+1], tq1);
    }
}

// ---------------------------------------------------------------------------
// Wtb[n'][k] bf16, gate-interleaved column permutation:
// n' = group*64 + gate*16 + c16  ->  orig j = gate*128 + group*16 + c16
// k: [0,136) Wih, [136,160) zero, [160,288) Whh.  b4p[n'] = bih[j]+bhh[j].
// ---------------------------------------------------------------------------
__global__ void prep_wtb(const float* __restrict__ Wih, const float* __restrict__ Whh,
                         const float* __restrict__ bih, const float* __restrict__ bhh,
                         bf16* __restrict__ Wtb, float* __restrict__ b4p)
{
    const int np = blockIdx.x;
    const int k  = threadIdx.x;
    const int gate = (np>>4)&3;
    const int j = gate*128 + (np>>6)*16 + (np&15);
    if (k < KP) {
        float v = 0.f;
        if (k < 136)      v = Wih[(long)j*136 + k];
        else if (k >= 160) v = Whh[(long)j*128 + (k-160)];
        Wtb[(long)np*KP + k] = (bf16)v;
    }
    if (k == 0) b4p[np] = bih[j] + bhh[j];
}

// ---------------------------------------------------------------------------
// BN scale/shift + collapse W2@W1 head.
// ---------------------------------------------------------------------------
__global__ void prep_stats(const float* __restrict__ stats,
    const float* __restrict__ g1, const float* __restrict__ beta1,
    const float* __restrict__ g2, const float* __restrict__ beta2,
    const float* __restrict__ W1, const float* __restrict__ b1,
    const float* __restrict__ W2, const float* __restrict__ b2,
    float* __restrict__ ss, float* __restrict__ wvb)
{
    const int t = threadIdx.x;
    const float inv = 1.f/(float)LN;
    if (t < 32) {
        float mean = stats[t]*inv;
        float var  = stats[32+t]*inv - mean*mean;
        float sc = g1[t]/sqrtf(var + 1e-5f);
        ss[t] = sc; ss[32+t] = beta1[t] - mean*sc;
    } else if (t < 64) {
        int c = t - 32;
        float mean = stats[64+c]*inv;
        float var  = stats[96+c]*inv - mean*mean;
        float sc = g2[c]/sqrtf(var + 1e-5f);
        ss[64+c] = sc; ss[96+c] = beta2[c] - mean*sc;
    }
    float s = 0.f;
    for (int a=0;a<20;++a) s += W2[a]*W1[a*HH + t];
    wvb[t] = s;
    if (t == 0) {
        float sb = 0.f;
        for (int a=0;a<20;++a) sb += W2[a]*b1[a];
        wvb[128] = sb + b2[0];
    }
}

// ---------------------------------------------------------------------------
// Build A[n][k] bf16 (row stride 288): [op16|attr56|fd32|od32|0*24|gh128]
// 32 rows/block; thread handles one 8-elem chunk per iter (all section
// boundaries are multiples of 8).
// ---------------------------------------------------------------------------
__global__ __launch_bounds__(256) void build_a(
    const float* __restrict__ op, const float* __restrict__ attr,
    const bf16* __restrict__ actf, const bf16* __restrict__ acto,
    const int* __restrict__ map, const float* __restrict__ ss,
    const bf16* __restrict__ h_prev, bf16* __restrict__ A,
    int l, int first)
{
    const int n0 = blockIdx.x * 32;
    const long lbase = (long)l * NN;
    for (int i = threadIdx.x; i < 32*36; i += 256) {
        const int r = i / 36, c = i - r*36;
        const long n = n0 + r;
        const long e = lbase + n;
        const int k0 = c*8;
        bf16x8 out;
        if (c < 9) {                                   // op (c<2) or attr
            const float* src = (c < 2) ? (op + e*16 + k0) : (attr + e*56 + (k0-16));
            float4 f0 = *(const float4*)src;
            float4 f1 = *(const float4*)(src+4);
            out[0]=(bf16)f0.x; out[1]=(bf16)f0.y; out[2]=(bf16)f0.z; out[3]=(bf16)f0.w;
            out[4]=(bf16)f1.x; out[5]=(bf16)f1.y; out[6]=(bf16)f1.z; out[7]=(bf16)f1.w;
        } else if (c < 17) {                           // fd / od with BN fold
            const int ch = (c < 13) ? (k0-72) : (k0-104);
            const bf16* src = (c < 13) ? (actf + e*32 + ch) : (acto + e*32 + ch);
            const float* s = ss + ((c < 13) ? 0 : 64);
            bf16x8 v = *(const bf16x8*)src;
            #pragma unroll
            for (int j=0;j<8;++j)
                out[j] = (bf16)fmaf((float)v[j], s[ch+j], s[32+ch+j]);
        } else if (c < 20) {                           // zero pad
            #pragma unroll
            for (int j=0;j<8;++j) out[j] = (bf16)0.f;
        } else {                                       // gh gather
            const int jj = k0 - 160;
            float g[8] = {0,0,0,0,0,0,0,0};
            if (!first) {
                int2 mp = *(const int2*)&map[e*2];
                if (mp.x) { bf16x8 v = *(const bf16x8*)&h_prev[(long)(mp.x-1)*HH + jj];
                    #pragma unroll
                    for (int j=0;j<8;++j) g[j] += (float)v[j]; }
                if (mp.y) { bf16x8 v = *(const bf16x8*)&h_prev[(long)(mp.y-1)*HH + jj];
                    #pragma unroll
                    for (int j=0;j<8;++j) g[j] += (float)v[j]; }
            }
            #pragma unroll
            for (int j=0;j<8;++j) out[j] = (bf16)(0.5f*g[j]);
        }
        *(bf16x8*)&A[n*KP + k0] = out;
    }
}

// ---------------------------------------------------------------------------
// MFMA GEMM + fused LSTM cell. 128x128 tile, BK=32, 9 k-steps.
// 4 waves in 2x2; wave tile 64x64 = 4x4 of 16x16x32 bf16 MFMA.
// Gate-interleaved B => wave's 4 n-tiles = gates i,f,g,o of same 16 cells.
// LDS slot swizzle q^((row>>1)&3) keeps frag ds_read_b128 conflict-free and
// stays compatible with global_load_lds's base+lane*16 destination rule.
// ---------------------------------------------------------------------------
__global__ __launch_bounds__(256) void lstm_gemm(
    const bf16* __restrict__ A, const bf16* __restrict__ Wtb,
    const float* __restrict__ b4p, const int* __restrict__ map,
    const float* __restrict__ c_prev, float* __restrict__ c_next,
    bf16* __restrict__ h_next, int l, int first)
{
    __shared__ bf16 As[128*32];
    __shared__ bf16 Bs[128*32];
    const int tid  = threadIdx.x;
    const int bm   = blockIdx.x;          // 0..127 (fast dim -> siblings share XCD)
    const int bn   = blockIdx.y;          // 0..3
    const int m0   = bm*128, n0p = bn*128;
    const int lane = tid & 63, w = tid >> 6;
    const int wr   = w >> 1,  wc = w & 1;

    f32x4 acc[4][4];
    #pragma unroll
    for (int ni=0; ni<4; ++ni){
        float b = b4p[n0p + wc*64 + ni*16 + (lane&15)];
        #pragma unroll
        for (int mi=0; mi<4; ++mi) acc[mi][ni] = (f32x4){b,b,b,b};
    }

    const bf16* Ab = A   + (size_t)m0*KP;
    const bf16* Bb = Wtb + (size_t)n0p*KP;
    const int lrr = lane >> 2;
    const int qs  = lane & 3;

    for (int kk=0; kk<9; ++kk){
        __syncthreads();
        #pragma unroll
        for (int hh=0; hh<2; ++hh){
            const int lr = w*32 + hh*16 + lrr;
            const int q  = qs ^ ((lr>>1)&3);
            const size_t go = (size_t)lr*KP + kk*32 + q*8;
            gld16(Ab + go, &As[(w*32 + hh*16)*32]);
            gld16(Bb + go, &Bs[(w*32 + hh*16)*32]);
        }
        __syncthreads();
        bf16x8 af[4], bfr[4];
        #pragma unroll
        for (int t4=0; t4<4; ++t4){
            const int am = wr*64 + t4*16 + (lane&15);
            af[t4] = *(const bf16x8*)&As[am*32 + (((lane>>4) ^ ((am>>1)&3))<<3)];
            const int bn_ = wc*64 + t4*16 + (lane&15);
            bfr[t4] = *(const bf16x8*)&Bs[bn_*32 + (((lane>>4) ^ ((bn_>>1)&3))<<3)];
        }
        #pragma unroll
        for (int mi=0; mi<4; ++mi)
            #pragma unroll
            for (int ni=0; ni<4; ++ni)
                acc[mi][ni] = __builtin_amdgcn_mfma_f32_16x16x32_bf16(
                    af[mi], bfr[ni], acc[mi][ni], 0, 0, 0);
    }

    // fused LSTM cell epilogue: gates i,f,g,o are acc[mi][0..3], same lane
    const long lbase = (long)l * NN;
    const int cell = bn*32 + wc*16 + (lane&15);
    #pragma unroll
    for (int mi=0; mi<4; ++mi){
        const int rbase = m0 + wr*64 + mi*16 + (lane>>4)*4;
        #pragma unroll
        for (int reg=0; reg<4; ++reg){
            const int n = rbase + reg;
            float gc = 0.f;
            if (!first){
                int2 mp = *(const int2*)&map[(lbase+n)*2];
                if (mp.x) gc += c_prev[(long)(mp.x-1)*HH + cell];
                if (mp.y) gc += c_prev[(long)(mp.y-1)*HH + cell];
                gc *= 0.5f;
            }
            float cn = sigm(acc[mi][1][reg])*gc
                     + sigm(acc[mi][0][reg])*tanhfast(acc[mi][2][reg]);
            float hn = sigm(acc[mi][3][reg])*tanhfast(cn);
            c_next[(long)n*HH + cell] = cn;
            h_next[(long)n*HH + cell] = (bf16)hn;
        }
    }
}

// ---------------------------------------------------------------------------
// out[n] = sigmoid(h[n] . wv + wb); one wave per row.
// ---------------------------------------------------------------------------
__global__ __launch_bounds__(256) void final_k(
    const bf16* __restrict__ h, const float* __restrict__ wvb,
    float* __restrict__ out, int rows)
{
    int gt = blockIdx.x*256 + threadIdx.x;
    int row = gt >> 6;
    int lane = gt & 63;
    if (row >= rows) return;
    float v = fmaf((float)h[(long)row*HH + lane], wvb[lane],
                   (float)h[(long)row*HH + 64 + lane] * wvb[64+lane]);
    #pragma unroll
    for (int off=32; off>0; off>>=1) v += __shfl_down(v, off);
    if (lane == 0) out[row] = sigm(v + wvb[128]);
}

extern "C" void kernel_launch(void* const* d_in, const int* in_sizes, int n_in,
                              void* d_out, int out_size, void* d_ws, size_t ws_size,
                              hipStream_t stream)
{
    const float* op      = (const float*)d_in[0];
    const float* attr    = (const float*)d_in[1];
    const float* filt    = (const float*)d_in[2];
    const float* outp    = (const float*)d_in[3];
    const int*   mapping = (const int*)d_in[4];
    const float* Wf  = (const float*)d_in[6];
    const float* bf_ = (const float*)d_in[7];
    const float* Wo  = (const float*)d_in[8];
    const float* bo  = (const float*)d_in[9];
    const float* g1  = (const float*)d_in[10];
    const float* be1 = (const float*)d_in[11];
    const float* g2  = (const float*)d_in[12];
    const float* be2 = (const float*)d_in[13];
    const float* Wih = (const float*)d_in[14];
    const float* Whh = (const float*)d_in[15];
    const float* bih = (const float*)d_in[16];
    const float* bhh = (const float*)d_in[17];
    const float* W1  = (const float*)d_in[18];
    const float* b1  = (const float*)d_in[19];
    const float* W2  = (const float*)d_in[20];
    const float* b2  = (const float*)d_in[21];

    char* p = (char*)d_ws;
    auto alloc = [&](size_t bytes){ char* r = p; p += (bytes + 255) & ~255ull; return r; };
    bf16* actf = (bf16*)alloc((size_t)LN*32*2);
    bf16* acto = (bf16*)alloc((size_t)LN*32*2);
    bf16* h0   = (bf16*)alloc((size_t)NN*HH*2);
    bf16* h1   = (bf16*)alloc((size_t)NN*HH*2);
    float* c0  = (float*)alloc((size_t)NN*HH*4);
    float* c1  = (float*)alloc((size_t)NN*HH*4);
    bf16* Abuf = (bf16*)alloc((size_t)NN*KP*2);
    bf16* Wtb  = (bf16*)alloc((size_t)512*KP*2);
    float* b4p = (float*)alloc(512*4);
    float* stats=(float*)alloc(128*4);
    float* ssb = (float*)alloc(128*4);
    float* wvb = (float*)alloc(132*4);

    hipMemsetAsync(stats, 0, 128*sizeof(float), stream);
    act_kernel<74><<<768, 256, 0, stream>>>(filt, Wf, bf_, actf, stats);
    act_kernel<32><<<768, 256, 0, stream>>>(outp, Wo, bo, acto, stats+64);
    prep_wtb<<<512, 320, 0, stream>>>(Wih, Whh, bih, bhh, Wtb, b4p);
    prep_stats<<<1, 128, 0, stream>>>(stats, g1, be1, g2, be2, W1, b1, W2, b2, ssb, wvb);

    bf16*  hb[2] = {h0, h1};
    float* cb[2] = {c0, c1};
    for (int t = 0; t < LL; ++t) {
        const int l = (LL-1) - t;
        const int first = (t == 0);
        build_a<<<NN/32, 256, 0, stream>>>(op, attr, actf, acto, mapping, ssb,
                                           hb[t&1], Abuf, l, first);
        lstm_gemm<<<dim3(128,4), 256, 0, stream>>>(Abuf, Wtb, b4p, mapping,
            cb[t&1], cb[(t+1)&1], hb[(t+1)&1], l, first);
    }
    final_k<<<(out_size*64 + 255)/256, 256, 0, stream>>>(hb[0], wvb, (float*)d_out, out_size);
}